// Round 15
// baseline (229.162 us; speedup 1.0000x reference)
//
#include <hip/hip_runtime.h>
#include <stdint.h>

#define N_ROWS 4096
#define D_DIM  1024
#define N_CAND 8192
#define TEMP_INV 20.0f
#define QSCALE 508.0f
#define OUT_SCALE (TEMP_INV / (QSCALE * QSCALE))

#define BM 256
#define BN 512
#define BK 64
#define NT 16        // K-tiles
#define BUFSZ 49152  // A(16K) + B(32K)

typedef __attribute__((ext_vector_type(4))) int i32x4;

using gvoid = __attribute__((address_space(1))) void;
using lvoid = __attribute__((address_space(3))) void;

#define BAR() __builtin_amdgcn_s_barrier()
#define SCHED0() __builtin_amdgcn_sched_barrier(0)

// ---------------------------------------------------------------------------
// Kernel 1: normalize rows, quantize to int8 (q = rint(x*508), clamp +-127),
// natural column order. cand = [P; N]. Also zeroes rowsum.
// ---------------------------------------------------------------------------
__global__ __launch_bounds__(256) void prep_kernel(
    const float* __restrict__ s, const float* __restrict__ p,
    const float* __restrict__ ng, unsigned char* __restrict__ s_q,
    unsigned char* __restrict__ cand_q, float* __restrict__ rowsum) {
  const int row = blockIdx.x;
  const int t = threadIdx.x;
  const float* src;
  unsigned char* dst;
  if (row < N_ROWS) {
    src = s + (size_t)row * D_DIM;
    dst = s_q + (size_t)row * D_DIM;
  } else if (row < 2 * N_ROWS) {
    src = p + (size_t)(row - N_ROWS) * D_DIM;
    dst = cand_q + (size_t)(row - N_ROWS) * D_DIM;
  } else {
    src = ng + (size_t)(row - 2 * N_ROWS) * D_DIM;
    dst = cand_q + (size_t)(row - N_ROWS) * D_DIM;
  }

  float4 v = reinterpret_cast<const float4*>(src)[t];
  float ss = v.x * v.x + v.y * v.y + v.z * v.z + v.w * v.w;
#pragma unroll
  for (int m = 32; m >= 1; m >>= 1) ss += __shfl_xor(ss, m, 64);
  __shared__ float red[4];
  const int w = t >> 6, l = t & 63;
  if (l == 0) red[w] = ss;
  __syncthreads();
  const float tot = red[0] + red[1] + red[2] + red[3];
  const float qs = QSCALE / fmaxf(sqrtf(tot), 1e-8f);

  auto q8 = [&](float x) -> unsigned {
    return (unsigned)((int)rintf(fminf(fmaxf(x * qs, -127.0f), 127.0f))) &
           0xffu;
  };
  const unsigned pk =
      q8(v.x) | (q8(v.y) << 8) | (q8(v.z) << 16) | (q8(v.w) << 24);
  *reinterpret_cast<unsigned*>(dst + t * 4) = pk;

  if (t == 0 && row < N_ROWS) rowsum[row] = 0.0f;
}

// ---------------------------------------------------------------------------
// Kernel 2: fused i8 GEMM + exp-rowsum. 256x512 block tile, BK=64, 512 thr =
// 8 waves (2Mx4N), per-wave 128x128 = 8x8 frags of mfma_i32_16x16x64_i8
// (acc = 256 AGPRs -- the r13-verified AGPR path; af/bf 64 VGPR).
// Grid 16x16 = 256 blocks = exactly 1/CU, ONE round (r13 paid 2).
// Per tile per wave: 16 ds_read_b128 + 64 MFMA (read:MFMA 1.7x better than
// r13). 3-buffer LDS ring (144 KB), staged 2 ahead (6 loads/thread/tile),
// one barrier per K-tile, counted vmcnt(6) (0 only at tail). LDS 16B-slot
// rotation phys=(g+(rl>>1))&3 (r7/r13-verified conflict-free); staging
// inverse-permutes the global source, LDS dst linear.
// ---------------------------------------------------------------------------
__global__ __launch_bounds__(512) void gemm_lse_kernel(
    const unsigned char* __restrict__ s_q,
    const unsigned char* __restrict__ cand_q,
    float* __restrict__ rowsum, float* __restrict__ pos) {
  __shared__ __align__(16) unsigned char lds[3 * BUFSZ];  // 144 KB

  const int t = threadIdx.x;
  const int w = t >> 6;
  const int l = t & 63;
  const int g = l >> 4;    // k-slice group: lane's 16B = k g*16..g*16+15
  const int rl = l & 15;   // lane within group
  const int wm = w >> 2;   // 0..1 (wave M half, 128 rows)
  const int wn = w & 3;    // 0..3 (wave N quarter, 128 cols)
  const int slot = (g + (rl >> 1)) & 3;  // phys 16B-slot, lane-constant
  const int rowBase = blockIdx.y * BM;
  const int colBase = blockIdx.x * BN;

  i32x4 acc[8][8] = {};  // 256 AGPR
  i32x4 af[8];
  i32x4 bf[8];

  // staging: thread t -> phys slot (t&3) of row (t>>2) within a 128-row
  // half; linear LDS dst t*16; fetch logical slot = ((t&3) - (t>>3)) & 3.
  const int sRow = t >> 2;                      // 0..127
  const int sSlotL = ((t & 3) - (t >> 3)) & 3;  // logical slot to fetch
  const unsigned char* gA =
      s_q + (size_t)(rowBase + sRow) * D_DIM + sSlotL * 16;
  const unsigned char* gB =
      cand_q + (size_t)(colBase + sRow) * D_DIM + sSlotL * 16;

  auto stage = [&](int T, int buf) {
    const size_t ko = (size_t)T * 64;
#pragma unroll
    for (int h = 0; h < 2; ++h)
      __builtin_amdgcn_global_load_lds(
          (const gvoid*)(gA + ko + (size_t)h * (128 * D_DIM)),
          (lvoid*)(lds + buf + h * 8192 + t * 16), 16, 0, 0);
#pragma unroll
    for (int h = 0; h < 4; ++h)
      __builtin_amdgcn_global_load_lds(
          (const gvoid*)(gB + ko + (size_t)h * (128 * D_DIM)),
          (lvoid*)(lds + buf + 16384 + h * 8192 + t * 16), 16, 0, 0);
  };

  // --- prologue: stage tiles 0,1; wait tile 0 (tile 1's 6 stay in flight).
  int b0 = 0, b1 = BUFSZ, b2 = 2 * BUFSZ;  // ring offsets
  stage(0, b0); stage(1, b1);
  asm volatile("s_waitcnt vmcnt(6)" ::: "memory");
  SCHED0();
  BAR(); SCHED0();

  for (int T = 0; T < NT; ++T) {
    const unsigned char* A = lds + b0;
    const unsigned char* B = A + 16384;
#pragma unroll
    for (int m = 0; m < 8; ++m) {
      const int r = wm * 128 + m * 16 + rl;
      af[m] = *reinterpret_cast<const i32x4*>(A + r * 64 + slot * 16);
    }
#pragma unroll
    for (int n = 0; n < 8; ++n) {
      const int r = wn * 128 + n * 16 + rl;
      bf[n] = *reinterpret_cast<const i32x4*>(B + r * 64 + slot * 16);
    }
    if (T + 2 < NT) stage(T + 2, b2);

    __builtin_amdgcn_s_setprio(1);
#pragma unroll
    for (int m = 0; m < 8; ++m)
#pragma unroll
      for (int n = 0; n < 8; ++n)
        acc[m][n] = __builtin_amdgcn_mfma_i32_16x16x64_i8(
            af[m], bf[n], acc[m][n], 0, 0, 0);
    __builtin_amdgcn_s_setprio(0);

    if (T + 2 < NT) {
      asm volatile("s_waitcnt vmcnt(6)" ::: "memory");  // T+1 landed
    } else if (T == NT - 2) {
      asm volatile("s_waitcnt vmcnt(0)" ::: "memory");  // tail drain
    }
    SCHED0();
    BAR(); SCHED0();

    const int tmp = b0; b0 = b1; b1 = b2; b2 = tmp;  // rotate ring
  }

  // --- epilogue: sim = acc * 20/508^2; cosine<=1 -> fixed-max LSE at 20.
  // i32 16x16 C/D layout (dtype-independent): col = l&15, row = g*4 + reg.
  __syncthreads();
  float* red = reinterpret_cast<float*>(lds);
  if (t < BM) red[t] = 0.0f;
  __syncthreads();

#pragma unroll
  for (int m = 0; m < 8; ++m) {
#pragma unroll
    for (int j = 0; j < 4; ++j) {
      const int rloc = wm * 128 + m * 16 + g * 4 + j;
      const int rowg = rowBase + rloc;
      float sm = 0.0f;
#pragma unroll
      for (int n = 0; n < 8; ++n) {
        const int colg = colBase + wn * 128 + n * 16 + rl;
        const float simv = (float)acc[m][n][j] * OUT_SCALE;
        if (colg == rowg) pos[rowg] = simv;
        sm += __expf(simv - TEMP_INV);
      }
      sm += __shfl_xor(sm, 1, 64);
      sm += __shfl_xor(sm, 2, 64);
      sm += __shfl_xor(sm, 4, 64);
      sm += __shfl_xor(sm, 8, 64);
      if (rl == 0) atomicAdd(&red[rloc], sm);
    }
  }
  __syncthreads();
  if (t < BM) atomicAdd(&rowsum[rowBase + t], red[t]);
}

// ---------------------------------------------------------------------------
// Kernel 3: loss = mean(20 + log(rowsum) - pos)
// ---------------------------------------------------------------------------
__global__ __launch_bounds__(1024) void loss_kernel(
    const float* __restrict__ rowsum, const float* __restrict__ pos,
    float* __restrict__ out) {
  const int t = threadIdx.x;
  float acc = 0.0f;
  for (int i = t; i < N_ROWS; i += 1024)
    acc += TEMP_INV + logf(rowsum[i]) - pos[i];
#pragma unroll
  for (int m = 32; m >= 1; m >>= 1) acc += __shfl_xor(acc, m, 64);
  __shared__ float red[16];
  const int w = t >> 6, l = t & 63;
  if (l == 0) red[w] = acc;
  __syncthreads();
  if (t == 0) {
    float tot = 0.0f;
#pragma unroll
    for (int i = 0; i < 16; ++i) tot += red[i];
    out[0] = tot / (float)N_ROWS;
  }
}

// ---------------------------------------------------------------------------
extern "C" void kernel_launch(void* const* d_in, const int* in_sizes, int n_in,
                              void* d_out, int out_size, void* d_ws,
                              size_t ws_size, hipStream_t stream) {
  (void)in_sizes; (void)n_in; (void)out_size; (void)ws_size;
  const float* s = (const float*)d_in[0];
  const float* p = (const float*)d_in[1];
  const float* ng = (const float*)d_in[2];

  unsigned char* s_q = (unsigned char*)d_ws;                      // 4 MB
  unsigned char* cand_q = s_q + (size_t)N_ROWS * D_DIM;           // 8 MB
  float* rowsum = (float*)(cand_q + (size_t)N_CAND * D_DIM);      // 16 KB
  float* pos = rowsum + N_ROWS;                                   // 16 KB
  float* out = (float*)d_out;

  prep_kernel<<<dim3(3 * N_ROWS), dim3(256), 0, stream>>>(s, p, ng, s_q,
                                                          cand_q, rowsum);
  gemm_lse_kernel<<<dim3(N_CAND / BN, N_ROWS / BM), dim3(512), 0, stream>>>(
      s_q, cand_q, rowsum, pos);
  loss_kernel<<<dim3(1), dim3(1024), 0, stream>>>(rowsum, pos, out);
}

// Round 16
// 64.298 us; speedup vs baseline: 3.5641x; 3.5641x over previous
//
#include <hip/hip_runtime.h>
#include <stdint.h>

#define N_ROWS 4096
#define D_DIM  1024
#define N_CAND 8192
#define TEMP_INV 20.0f
#define QSCALE 508.0f
#define OUT_SCALE (TEMP_INV / (QSCALE * QSCALE))

#define BM 256
#define BN 256
#define BK 64
#define NT 16  // K-tiles

typedef __attribute__((ext_vector_type(4))) int i32x4;

using gvoid = __attribute__((address_space(1))) void;
using lvoid = __attribute__((address_space(3))) void;

#define BAR() __builtin_amdgcn_s_barrier()
#define SCHED0() __builtin_amdgcn_sched_barrier(0)
#define LGKM0() do { asm volatile("s_waitcnt lgkmcnt(0)" ::: "memory"); \
                     __builtin_amdgcn_sched_barrier(0); } while (0)

// ---------------------------------------------------------------------------
// Kernel 1: normalize rows, quantize to int8 (q = rint(x*508), clamp +-127),
// natural column order. cand = [P; N]. Also zeroes rowsum.
// ---------------------------------------------------------------------------
__global__ __launch_bounds__(256) void prep_kernel(
    const float* __restrict__ s, const float* __restrict__ p,
    const float* __restrict__ ng, unsigned char* __restrict__ s_q,
    unsigned char* __restrict__ cand_q, float* __restrict__ rowsum) {
  const int row = blockIdx.x;
  const int t = threadIdx.x;
  const float* src;
  unsigned char* dst;
  if (row < N_ROWS) {
    src = s + (size_t)row * D_DIM;
    dst = s_q + (size_t)row * D_DIM;
  } else if (row < 2 * N_ROWS) {
    src = p + (size_t)(row - N_ROWS) * D_DIM;
    dst = cand_q + (size_t)(row - N_ROWS) * D_DIM;
  } else {
    src = ng + (size_t)(row - 2 * N_ROWS) * D_DIM;
    dst = cand_q + (size_t)(row - N_ROWS) * D_DIM;
  }

  float4 v = reinterpret_cast<const float4*>(src)[t];
  float ss = v.x * v.x + v.y * v.y + v.z * v.z + v.w * v.w;
#pragma unroll
  for (int m = 32; m >= 1; m >>= 1) ss += __shfl_xor(ss, m, 64);
  __shared__ float red[4];
  const int w = t >> 6, l = t & 63;
  if (l == 0) red[w] = ss;
  __syncthreads();
  const float tot = red[0] + red[1] + red[2] + red[3];
  const float qs = QSCALE / fmaxf(sqrtf(tot), 1e-8f);

  auto q8 = [&](float x) -> unsigned {
    return (unsigned)((int)rintf(fminf(fmaxf(x * qs, -127.0f), 127.0f))) &
           0xffu;
  };
  const unsigned pk =
      q8(v.x) | (q8(v.y) << 8) | (q8(v.z) << 16) | (q8(v.w) << 24);
  *reinterpret_cast<unsigned*>(dst + t * 4) = pk;

  if (t == 0 && row < N_ROWS) rowsum[row] = 0.0f;
}

// ---------------------------------------------------------------------------
// Kernel 2: fused i8 GEMM + exp-rowsum. 256x256 tile, BK=64, 512 thr =
// 8 waves (2Mx4N), wave 128x64 = 8x4 frags of mfma_i32_16x16x64_i8
// (acc 128 AGPR + ~95 arch VGPR = ~223 <= 256 unified cap -- the r13
// no-spill budget; r15 proved VGPR+AGPR <= 256/wave is the invariant).
// KEY CHANGE vs r13 (m201 T3 port): each K-tile split into 2 phases of
// 16 MFMA with {reads || stage -> barrier -> lgkmcnt(0) -> setprio+MFMA ->
// barrier}; P0 = bf[0:4]+af[0:4] reads + stage A(T+2), MFMA m0-3;
// P1 = af[4:8] reads (reusing af regs) + stage B(T+2), MFMA m4-7,
// counted vmcnt(4) (0 only at tail). Barrier-per-phase bounds wave skew
// to 1 phase (4-buffer ring stays overwrite-safe); cross-wave lgkm
// stagger lets MFMA clusters cover sibling waves' LDS drain.
// LDS slot rotation phys=(g+(rl>>1))&3 (conflict-free, r7/r13-verified).
// ---------------------------------------------------------------------------
__global__ __launch_bounds__(512) void gemm_lse_kernel(
    const unsigned char* __restrict__ s_q,
    const unsigned char* __restrict__ cand_q,
    float* __restrict__ rowsum, float* __restrict__ pos) {
  __shared__ __align__(16) unsigned char lds[4 * 32768];  // 4 x (A16K|B16K)

  const int t = threadIdx.x;
  const int w = t >> 6;
  const int l = t & 63;
  const int g = l >> 4;    // k-slice group: lane's 16B = k g*16..g*16+15
  const int rl = l & 15;   // lane within group
  const int wm = w >> 2;   // 0..1 (wave M half)
  const int wn = w & 3;    // 0..3 (wave N quarter)
  const int slot = (g + (rl >> 1)) & 3;  // phys 16B-slot, lane-constant
  const int rowBase = blockIdx.y * BM;
  const int colBase = blockIdx.x * BN;

  i32x4 acc[8][4] = {};  // 128 AGPR (plain-MFMA path)
  i32x4 af[4];           // reused across both phases (16 VGPR)
  i32x4 bf[4];           // 16 VGPR

  // staging: thread t -> phys slot (t&3) of local row (t>>2), linear LDS
  // dst t*16; fetch logical slot = ((t&3) - (t>>3)) & 3  (r7-verified).
  const int sRow = t >> 2;                      // 0..127
  const int sSlotL = ((t & 3) - (t >> 3)) & 3;  // logical slot to fetch
  const unsigned char* gA =
      s_q + (size_t)(rowBase + sRow) * D_DIM + sSlotL * 16;
  const unsigned char* gB =
      cand_q + (size_t)(colBase + sRow) * D_DIM + sSlotL * 16;

  auto stageA = [&](int T) {
    const int buf = (T & 3) * 32768;
    const size_t ko = (size_t)T * 64;
#pragma unroll
    for (int h = 0; h < 2; ++h)
      __builtin_amdgcn_global_load_lds(
          (const gvoid*)(gA + ko + (size_t)h * (128 * D_DIM)),
          (lvoid*)(lds + buf + h * 8192 + t * 16), 16, 0, 0);
  };
  auto stageB = [&](int T) {
    const int buf = (T & 3) * 32768;
    const size_t ko = (size_t)T * 64;
#pragma unroll
    for (int h = 0; h < 2; ++h)
      __builtin_amdgcn_global_load_lds(
          (const gvoid*)(gB + ko + (size_t)h * (128 * D_DIM)),
          (lvoid*)(lds + buf + 16384 + h * 8192 + t * 16), 16, 0, 0);
  };

  // --- prologue: stage tiles 0,1; wait tile 0 (tile 1's 4 stay in flight).
  stageA(0); stageB(0); stageA(1); stageB(1);
  asm volatile("s_waitcnt vmcnt(4)" ::: "memory");
  SCHED0();
  BAR(); SCHED0();

  for (int T = 0; T < NT; ++T) {
    const unsigned char* A = lds + (T & 3) * 32768;
    const unsigned char* B = A + 16384;
    const bool sN = (T + 2 < NT);

    // ---- P0: bf[0:4] + af[0:4] reads | stage A(T+2) | 16 MFMA (m0-3) ----
#pragma unroll
    for (int n = 0; n < 4; ++n) {
      const int r = wn * 64 + n * 16 + rl;
      bf[n] = *reinterpret_cast<const i32x4*>(B + r * 64 + slot * 16);
    }
#pragma unroll
    for (int m = 0; m < 4; ++m) {
      const int r = wm * 128 + m * 16 + rl;
      af[m] = *reinterpret_cast<const i32x4*>(A + r * 64 + slot * 16);
    }
    if (sN) stageA(T + 2);
    BAR(); LGKM0();
    __builtin_amdgcn_s_setprio(1);
#pragma unroll
    for (int m = 0; m < 4; ++m)
#pragma unroll
      for (int n = 0; n < 4; ++n)
        acc[m][n] = __builtin_amdgcn_mfma_i32_16x16x64_i8(
            af[m], bf[n], acc[m][n], 0, 0, 0);
    __builtin_amdgcn_s_setprio(0);
    BAR();

    // ---- P1: af[4:8] reads (reuse regs) | stage B(T+2) | 16 MFMA (m4-7) --
#pragma unroll
    for (int m = 0; m < 4; ++m) {
      const int r = wm * 128 + (m + 4) * 16 + rl;
      af[m] = *reinterpret_cast<const i32x4*>(A + r * 64 + slot * 16);
    }
    if (sN) stageB(T + 2);
    BAR(); LGKM0();
    __builtin_amdgcn_s_setprio(1);
#pragma unroll
    for (int m = 0; m < 4; ++m)
#pragma unroll
      for (int n = 0; n < 4; ++n)
        acc[m + 4][n] = __builtin_amdgcn_mfma_i32_16x16x64_i8(
            af[m], bf[n], acc[m + 4][n], 0, 0, 0);
    __builtin_amdgcn_s_setprio(0);

    if (sN) {
      asm volatile("s_waitcnt vmcnt(4)" ::: "memory");  // T+1 landed
    } else if (T == NT - 2) {
      asm volatile("s_waitcnt vmcnt(0)" ::: "memory");  // tail drain
    }
    SCHED0();
    BAR(); SCHED0();
  }

  // --- epilogue: sim = acc * 20/508^2; cosine<=1 -> fixed-max LSE at 20.
  // i32 16x16 C/D layout (dtype-independent): col = l&15, row = g*4 + reg.
  __syncthreads();
  float* red = reinterpret_cast<float*>(lds);
  if (t < BM) red[t] = 0.0f;
  __syncthreads();

#pragma unroll
  for (int m = 0; m < 8; ++m) {
#pragma unroll
    for (int j = 0; j < 4; ++j) {
      const int rloc = wm * 128 + m * 16 + g * 4 + j;
      const int rowg = rowBase + rloc;
      float sm = 0.0f;
#pragma unroll
      for (int n = 0; n < 4; ++n) {
        const int colg = colBase + wn * 64 + n * 16 + rl;
        const float simv = (float)acc[m][n][j] * OUT_SCALE;
        if (colg == rowg) pos[rowg] = simv;
        sm += __expf(simv - TEMP_INV);
      }
      sm += __shfl_xor(sm, 1, 64);
      sm += __shfl_xor(sm, 2, 64);
      sm += __shfl_xor(sm, 4, 64);
      sm += __shfl_xor(sm, 8, 64);
      if (rl == 0) atomicAdd(&red[rloc], sm);
    }
  }
  __syncthreads();
  if (t < BM) atomicAdd(&rowsum[rowBase + t], red[t]);
}

// ---------------------------------------------------------------------------
// Kernel 3: loss = mean(20 + log(rowsum) - pos)
// ---------------------------------------------------------------------------
__global__ __launch_bounds__(1024) void loss_kernel(
    const float* __restrict__ rowsum, const float* __restrict__ pos,
    float* __restrict__ out) {
  const int t = threadIdx.x;
  float acc = 0.0f;
  for (int i = t; i < N_ROWS; i += 1024)
    acc += TEMP_INV + logf(rowsum[i]) - pos[i];
#pragma unroll
  for (int m = 32; m >= 1; m >>= 1) acc += __shfl_xor(acc, m, 64);
  __shared__ float red[16];
  const int w = t >> 6, l = t & 63;
  if (l == 0) red[w] = acc;
  __syncthreads();
  if (t == 0) {
    float tot = 0.0f;
#pragma unroll
    for (int i = 0; i < 16; ++i) tot += red[i];
    out[0] = tot / (float)N_ROWS;
  }
}

// ---------------------------------------------------------------------------
extern "C" void kernel_launch(void* const* d_in, const int* in_sizes, int n_in,
                              void* d_out, int out_size, void* d_ws,
                              size_t ws_size, hipStream_t stream) {
  (void)in_sizes; (void)n_in; (void)out_size; (void)ws_size;
  const float* s = (const float*)d_in[0];
  const float* p = (const float*)d_in[1];
  const float* ng = (const float*)d_in[2];

  unsigned char* s_q = (unsigned char*)d_ws;                      // 4 MB
  unsigned char* cand_q = s_q + (size_t)N_ROWS * D_DIM;           // 8 MB
  float* rowsum = (float*)(cand_q + (size_t)N_CAND * D_DIM);      // 16 KB
  float* pos = rowsum + N_ROWS;                                   // 16 KB
  float* out = (float*)d_out;

  prep_kernel<<<dim3(3 * N_ROWS), dim3(256), 0, stream>>>(s, p, ng, s_q,
                                                          cand_q, rowsum);
  gemm_lse_kernel<<<dim3(N_CAND / BN, N_ROWS / BM), dim3(512), 0, stream>>>(
      s_q, cand_q, rowsum, pos);
  loss_kernel<<<dim3(1), dim3(1024), 0, stream>>>(rowsum, pos, out);
}

// Round 17
// 58.645 us; speedup vs baseline: 3.9076x; 1.0964x over previous
//
#include <hip/hip_runtime.h>
#include <stdint.h>

#define N_ROWS 4096
#define D_DIM  1024
#define N_CAND 8192
#define TEMP_INV 20.0f
#define QSCALE 508.0f
#define OUT_SCALE (TEMP_INV / (QSCALE * QSCALE))

#define BM 256
#define BN 256
#define BK 64
#define NT 16  // K-tiles

typedef __attribute__((ext_vector_type(4))) int i32x4;

using gvoid = __attribute__((address_space(1))) void;
using lvoid = __attribute__((address_space(3))) void;

#define BAR() __builtin_amdgcn_s_barrier()
#define SCHED0() __builtin_amdgcn_sched_barrier(0)

// ---------------------------------------------------------------------------
// Kernel 1: normalize rows, quantize to int8 (q = rint(x*508), clamp +-127),
// natural column order. cand = [P; N]. Also zeroes rowsum.
// ---------------------------------------------------------------------------
__global__ __launch_bounds__(256) void prep_kernel(
    const float* __restrict__ s, const float* __restrict__ p,
    const float* __restrict__ ng, unsigned char* __restrict__ s_q,
    unsigned char* __restrict__ cand_q, float* __restrict__ rowsum) {
  const int row = blockIdx.x;
  const int t = threadIdx.x;
  const float* src;
  unsigned char* dst;
  if (row < N_ROWS) {
    src = s + (size_t)row * D_DIM;
    dst = s_q + (size_t)row * D_DIM;
  } else if (row < 2 * N_ROWS) {
    src = p + (size_t)(row - N_ROWS) * D_DIM;
    dst = cand_q + (size_t)(row - N_ROWS) * D_DIM;
  } else {
    src = ng + (size_t)(row - 2 * N_ROWS) * D_DIM;
    dst = cand_q + (size_t)(row - N_ROWS) * D_DIM;
  }

  float4 v = reinterpret_cast<const float4*>(src)[t];
  float ss = v.x * v.x + v.y * v.y + v.z * v.z + v.w * v.w;
#pragma unroll
  for (int m = 32; m >= 1; m >>= 1) ss += __shfl_xor(ss, m, 64);
  __shared__ float red[4];
  const int w = t >> 6, l = t & 63;
  if (l == 0) red[w] = ss;
  __syncthreads();
  const float tot = red[0] + red[1] + red[2] + red[3];
  const float qs = QSCALE / fmaxf(sqrtf(tot), 1e-8f);

  auto q8 = [&](float x) -> unsigned {
    return (unsigned)((int)rintf(fminf(fmaxf(x * qs, -127.0f), 127.0f))) &
           0xffu;
  };
  const unsigned pk =
      q8(v.x) | (q8(v.y) << 8) | (q8(v.z) << 16) | (q8(v.w) << 24);
  *reinterpret_cast<unsigned*>(dst + t * 4) = pk;

  if (t == 0 && row < N_ROWS) rowsum[row] = 0.0f;
}

// ---------------------------------------------------------------------------
// Kernel 2: fused i8 GEMM + exp-rowsum. 256x256 tile, BK=64, 1024 thr =
// 16 waves (4Mx4N), wave 64x64 = 4x4 frags of mfma_i32_16x16x64_i8.
// KEY CHANGE vs r13: 4 waves/SIMD (was 2) -- r13/r16 counters show a
// latency floor (MfmaUtil 27, VALU 23, LDS ~25%, HBM 6%: nothing
// saturated); doubling resident waves halves the un-hidden latency.
// Registers: acc[4][4] = 64 AGPR (plain-MFMA AGPR path, r13-proven) +
// af[4]+bf[4]+addr ~60 arch -- fits 4 waves/SIMD unified budget.
// 4-buffer LDS ring (128 KB, 1 block/CU), 2 gload_lds/thread/tile
// (1024 thr cover A 256x64 + B 256x64 in one shot), ONE barrier per
// K-tile, counted vmcnt(2) (0 only at tail). LDS slot rotation
// phys=(g+(rl>>1))&3 (conflict-free, r7/r13-verified); staging
// inverse-permutes the global source, LDS dst linear.
// ---------------------------------------------------------------------------
__global__ __launch_bounds__(1024) void gemm_lse_kernel(
    const unsigned char* __restrict__ s_q,
    const unsigned char* __restrict__ cand_q,
    float* __restrict__ rowsum, float* __restrict__ pos) {
  __shared__ __align__(16) unsigned char lds[4 * 32768];  // 4 x (A16K|B16K)

  const int t = threadIdx.x;
  const int w = t >> 6;
  const int l = t & 63;
  const int g = l >> 4;    // k-slice group: lane's 16B = k g*16..g*16+15
  const int rl = l & 15;   // lane within group
  const int wm = w >> 2;   // 0..3 (wave M quarter, 64 rows)
  const int wn = w & 3;    // 0..3 (wave N quarter, 64 cols)
  const int slot = (g + (rl >> 1)) & 3;  // phys 16B-slot, lane-constant
  const int rowBase = blockIdx.y * BM;
  const int colBase = blockIdx.x * BN;

  i32x4 acc[4][4] = {};  // 64 AGPR (plain-MFMA path)
  i32x4 af[4];           // 16 VGPR
  i32x4 bf[4];           // 16 VGPR

  // staging: thread t -> phys slot (t&3) of local row (t>>2) (0..255),
  // linear LDS dst t*16; fetch logical slot = ((t&3) - (t>>3)) & 3.
  const int sRow = t >> 2;                      // 0..255
  const int sSlotL = ((t & 3) - (t >> 3)) & 3;  // logical slot to fetch
  const unsigned char* gA =
      s_q + (size_t)(rowBase + sRow) * D_DIM + sSlotL * 16;
  const unsigned char* gB =
      cand_q + (size_t)(colBase + sRow) * D_DIM + sSlotL * 16;

  auto stage = [&](int T) {
    const int buf = (T & 3) * 32768;
    const size_t ko = (size_t)T * 64;
    __builtin_amdgcn_global_load_lds((const gvoid*)(gA + ko),
                                     (lvoid*)(lds + buf + t * 16), 16, 0, 0);
    __builtin_amdgcn_global_load_lds(
        (const gvoid*)(gB + ko),
        (lvoid*)(lds + buf + 16384 + t * 16), 16, 0, 0);
  };

  // --- prologue: stage tiles 0,1; wait tile 0 (tile 1's 2 stay in flight).
  stage(0); stage(1);
  asm volatile("s_waitcnt vmcnt(2)" ::: "memory");
  SCHED0();
  BAR(); SCHED0();

  for (int T = 0; T < NT; ++T) {
    const unsigned char* A = lds + (T & 3) * 32768;
    const unsigned char* B = A + 16384;
#pragma unroll
    for (int m = 0; m < 4; ++m) {
      const int r = wm * 64 + m * 16 + rl;
      af[m] = *reinterpret_cast<const i32x4*>(A + r * 64 + slot * 16);
    }
#pragma unroll
    for (int n = 0; n < 4; ++n) {
      const int r = wn * 64 + n * 16 + rl;
      bf[n] = *reinterpret_cast<const i32x4*>(B + r * 64 + slot * 16);
    }
    if (T + 2 < NT) stage(T + 2);

    __builtin_amdgcn_s_setprio(1);
#pragma unroll
    for (int m = 0; m < 4; ++m)
#pragma unroll
      for (int n = 0; n < 4; ++n)
        acc[m][n] = __builtin_amdgcn_mfma_i32_16x16x64_i8(
            af[m], bf[n], acc[m][n], 0, 0, 0);
    __builtin_amdgcn_s_setprio(0);

    if (T + 2 < NT) {
      asm volatile("s_waitcnt vmcnt(2)" ::: "memory");  // T+1 landed
    } else if (T == NT - 2) {
      asm volatile("s_waitcnt vmcnt(0)" ::: "memory");  // tail drain
    }
    SCHED0();
    BAR(); SCHED0();
  }

  // --- epilogue: sim = acc * 20/508^2; cosine<=1 -> fixed-max LSE at 20.
  // i32 16x16 C/D layout (dtype-independent): col = l&15, row = g*4 + reg.
  __syncthreads();
  float* red = reinterpret_cast<float*>(lds);
  if (t < BM) red[t] = 0.0f;
  __syncthreads();

#pragma unroll
  for (int m = 0; m < 4; ++m) {
#pragma unroll
    for (int j = 0; j < 4; ++j) {
      const int rloc = wm * 64 + m * 16 + g * 4 + j;
      const int rowg = rowBase + rloc;
      float sm = 0.0f;
#pragma unroll
      for (int n = 0; n < 4; ++n) {
        const int colg = colBase + wn * 64 + n * 16 + rl;
        const float simv = (float)acc[m][n][j] * OUT_SCALE;
        if (colg == rowg) pos[rowg] = simv;
        sm += __expf(simv - TEMP_INV);
      }
      sm += __shfl_xor(sm, 1, 64);
      sm += __shfl_xor(sm, 2, 64);
      sm += __shfl_xor(sm, 4, 64);
      sm += __shfl_xor(sm, 8, 64);
      if (rl == 0) atomicAdd(&red[rloc], sm);
    }
  }
  __syncthreads();
  if (t < BM) atomicAdd(&rowsum[rowBase + t], red[t]);
}

// ---------------------------------------------------------------------------
// Kernel 3: loss = mean(20 + log(rowsum) - pos)
// ---------------------------------------------------------------------------
__global__ __launch_bounds__(1024) void loss_kernel(
    const float* __restrict__ rowsum, const float* __restrict__ pos,
    float* __restrict__ out) {
  const int t = threadIdx.x;
  float acc = 0.0f;
  for (int i = t; i < N_ROWS; i += 1024)
    acc += TEMP_INV + logf(rowsum[i]) - pos[i];
#pragma unroll
  for (int m = 32; m >= 1; m >>= 1) acc += __shfl_xor(acc, m, 64);
  __shared__ float red[16];
  const int w = t >> 6, l = t & 63;
  if (l == 0) red[w] = acc;
  __syncthreads();
  if (t == 0) {
    float tot = 0.0f;
#pragma unroll
    for (int i = 0; i < 16; ++i) tot += red[i];
    out[0] = tot / (float)N_ROWS;
  }
}

// ---------------------------------------------------------------------------
extern "C" void kernel_launch(void* const* d_in, const int* in_sizes, int n_in,
                              void* d_out, int out_size, void* d_ws,
                              size_t ws_size, hipStream_t stream) {
  (void)in_sizes; (void)n_in; (void)out_size; (void)ws_size;
  const float* s = (const float*)d_in[0];
  const float* p = (const float*)d_in[1];
  const float* ng = (const float*)d_in[2];

  unsigned char* s_q = (unsigned char*)d_ws;                      // 4 MB
  unsigned char* cand_q = s_q + (size_t)N_ROWS * D_DIM;           // 8 MB
  float* rowsum = (float*)(cand_q + (size_t)N_CAND * D_DIM);      // 16 KB
  float* pos = rowsum + N_ROWS;                                   // 16 KB
  float* out = (float*)d_out;

  prep_kernel<<<dim3(3 * N_ROWS), dim3(256), 0, stream>>>(s, p, ng, s_q,
                                                          cand_q, rowsum);
  gemm_lse_kernel<<<dim3(N_CAND / BN, N_ROWS / BM), dim3(1024), 0, stream>>>(
      s_q, cand_q, rowsum, pos);
  loss_kernel<<<dim3(1), dim3(1024), 0, stream>>>(rowsum, pos, out);
}